// Round 8
// baseline (349.826 us; speedup 1.0000x reference)
//
#include <hip/hip_runtime.h>
#include <hip/hip_bf16.h>
#include <math.h>

// Problem dims (fixed by the reference)
#define NB 16
#define NT 2048
#define NR (NB*NT)     // 32768 rows
#define ND 128
#define NH 1024
#define NO 768
#define NK NT          // segment capacity K = T
#define K1_ROWS 32
#define NCH 32         // k_pool chunks per batch
#define TCH (NT/NCH)   // 64 t-steps per pool chunk
#define SC_THREADS 256
#define SC_PER (NT/SC_THREADS)   // 8
#define R_FILL 32      // rows per fill block
#define RKR 16         // candidate rows per k_mlp_real block

__device__ __forceinline__ float gelu_f(float x){
    // exact gelu: x * 0.5 * (1 + erf(x/sqrt(2)))
    return 0.5f * x * (1.0f + erff(x * 0.70710678118654752440f));
}
__device__ __forceinline__ void fma4(float4& a, float s, float4 w){
    a.x = fmaf(s, w.x, a.x);
    a.y = fmaf(s, w.y, a.y);
    a.z = fmaf(s, w.z, a.z);
    a.w = fmaf(s, w.w, a.w);
}

// ---------------------------------------------------------------------------
// K1: embedding gather + (row @ ctx_W + b) + LayerNorm + GELU + bnd/rst dots
// ---------------------------------------------------------------------------
__global__ __launch_bounds__(256) void k_embed_ctx(
    const int* __restrict__ inp, const float* __restrict__ emb,
    const float* __restrict__ Wc, const float* __restrict__ bc,
    const float* __restrict__ lng, const float* __restrict__ lnb,
    const float* __restrict__ bndW, const float* __restrict__ bndB,
    const float* __restrict__ rstW, const float* __restrict__ rstB,
    float* __restrict__ hout, float* __restrict__ xseq, int* __restrict__ rmask)
{
    __shared__ float sE[K1_ROWS][ND];   // 16 KB
    const int tid = threadIdx.x;
    const int r0 = blockIdx.x * K1_ROWS;

    #pragma unroll
    for (int q = 0; q < 4; q++){
        int fidx = tid + 256*q;
        int row  = fidx >> 5;
        int c4   = fidx & 31;
        int tokv = inp[r0 + row];
        float4 ev = make_float4(0.f, 0.f, 0.f, 0.f);
        if (tokv != 0) ev = ((const float4*)emb)[tokv*(ND/4) + c4];
        ((float4*)(&sE[row][0]))[c4] = ev;
    }
    __syncthreads();

    const int bun  = tid >> 5;
    const int lane = tid & 31;
    const int jo   = lane * 4;
    const int rbse = bun * 4;

    float4 acc0 = make_float4(0,0,0,0);
    float4 acc1 = acc0, acc2 = acc0, acc3 = acc0;

    for (int k0 = 0; k0 < ND; k0 += 4){
        float4 e0 = *(const float4*)&sE[rbse+0][k0];
        float4 e1 = *(const float4*)&sE[rbse+1][k0];
        float4 e2 = *(const float4*)&sE[rbse+2][k0];
        float4 e3 = *(const float4*)&sE[rbse+3][k0];
        float4 w0 = *(const float4*)&Wc[(k0+0)*ND + jo];
        float4 w1 = *(const float4*)&Wc[(k0+1)*ND + jo];
        float4 w2 = *(const float4*)&Wc[(k0+2)*ND + jo];
        float4 w3 = *(const float4*)&Wc[(k0+3)*ND + jo];
        fma4(acc0, e0.x, w0); fma4(acc0, e0.y, w1); fma4(acc0, e0.z, w2); fma4(acc0, e0.w, w3);
        fma4(acc1, e1.x, w0); fma4(acc1, e1.y, w1); fma4(acc1, e1.z, w2); fma4(acc1, e1.w, w3);
        fma4(acc2, e2.x, w0); fma4(acc2, e2.y, w1); fma4(acc2, e2.z, w2); fma4(acc2, e2.w, w3);
        fma4(acc3, e3.x, w0); fma4(acc3, e3.y, w1); fma4(acc3, e3.z, w2); fma4(acc3, e3.w, w3);
    }

    const float4 cb  = ((const float4*)bc)[lane];
    const float4 gv  = ((const float4*)lng)[lane];
    const float4 bv  = ((const float4*)lnb)[lane];
    const float4 bwv = ((const float4*)bndW)[lane];
    const float4 rwv = ((const float4*)rstW)[lane];
    const float bb0 = bndB[0], rr0 = rstB[0];

    #define K1_EPI(ACC, RR) do { \
        float4 a = ACC; \
        a.x += cb.x; a.y += cb.y; a.z += cb.z; a.w += cb.w; \
        float s_ = a.x + a.y + a.z + a.w; \
        float q_ = a.x*a.x + a.y*a.y + a.z*a.z + a.w*a.w; \
        for (int off = 16; off > 0; off >>= 1){ s_ += __shfl_xor(s_, off, 32); q_ += __shfl_xor(q_, off, 32); } \
        float m_ = s_ * (1.0f/ND); \
        float rstd_ = rsqrtf(q_ * (1.0f/ND) - m_*m_ + 1e-5f); \
        float4 hh; \
        hh.x = gelu_f((a.x - m_)*rstd_*gv.x + bv.x); \
        hh.y = gelu_f((a.y - m_)*rstd_*gv.y + bv.y); \
        hh.z = gelu_f((a.z - m_)*rstd_*gv.z + bv.z); \
        hh.w = gelu_f((a.w - m_)*rstd_*gv.w + bv.w); \
        *(float4*)&hout[(size_t)(r0 + rbse + RR)*ND + jo] = hh; \
        float pb = hh.x*bwv.x + hh.y*bwv.y + hh.z*bwv.z + hh.w*bwv.w; \
        float pr = hh.x*rwv.x + hh.y*rwv.y + hh.z*rwv.z + hh.w*rwv.w; \
        for (int off = 16; off > 0; off >>= 1){ pb += __shfl_xor(pb, off, 32); pr += __shfl_xor(pr, off, 32); } \
        if (lane == 0){ \
            int rg = r0 + rbse + RR; \
            xseq[rg]  = tanhf(pb + bb0); \
            rmask[rg] = (pr + rr0) > 0.f ? 1 : 0; \
        } \
    } while(0)

    K1_EPI(acc0, 0); K1_EPI(acc1, 1); K1_EPI(acc2, 2); K1_EPI(acc3, 3);
    #undef K1_EPI
}

// ---------------------------------------------------------------------------
// K2: parallel speculative LIF scan (affine charge; speculate-and-restart on
// conditional reset; converges in 1 pass when no (spike && reset)).
// ---------------------------------------------------------------------------
__global__ __launch_bounds__(SC_THREADS) void k_scan(
    const float* __restrict__ x, const int* __restrict__ rm,
    float* __restrict__ wout, int* __restrict__ ids, int* __restrict__ used)
{
    const int b   = blockIdx.x;
    const int tid = threadIdx.x;
    const int t0  = tid * SC_PER;

    float xv[SC_PER];
    int   rv[SC_PER];
    {
        const float4* xb4 = (const float4*)(x + b*NT + t0);
        float4 xa = xb4[0], xb = xb4[1];
        xv[0]=xa.x; xv[1]=xa.y; xv[2]=xa.z; xv[3]=xa.w;
        xv[4]=xb.x; xv[5]=xb.y; xv[6]=xb.z; xv[7]=xb.w;
        const int4* rb4 = (const int4*)(rm + b*NT + t0);
        int4 r0_ = rb4[0], r1_ = rb4[1];
        rv[0]=r0_.x; rv[1]=r0_.y; rv[2]=r0_.z; rv[3]=r0_.w;
        rv[4]=r1_.x; rv[5]=r1_.y; rv[6]=r1_.z; rv[7]=r1_.w;
    }

    __shared__ float sA[SC_THREADS], sB[SC_THREADS];
    __shared__ float sA2[SC_THREADS], sB2[SC_THREADS];
    __shared__ int   smin;

    float vkeep[SC_PER];
    #pragma unroll
    for (int i = 0; i < SC_PER; i++) vkeep[i] = 0.f;

    int s = 0;
    while (true){
        float aL = 1.f, bL = 0.f;
        #pragma unroll
        for (int i = 0; i < SC_PER; i++){
            if (t0 + i >= s){
                aL *= 0.5f;
                bL = 0.5f*(bL + xv[i]);
            }
        }
        sA[tid] = aL; sB[tid] = bL;
        __syncthreads();
        float *Ain = sA, *Bin = sB, *Aout = sA2, *Bout = sB2;
        for (int off = 1; off < SC_THREADS; off <<= 1){
            float a_cur = Ain[tid], b_cur = Bin[tid];
            float a_pre = 1.f, b_pre = 0.f;
            if (tid >= off){ a_pre = Ain[tid-off]; b_pre = Bin[tid-off]; }
            Aout[tid] = a_pre * a_cur;
            Bout[tid] = fmaf(a_cur, b_pre, b_cur);
            __syncthreads();
            float* t1 = Ain; Ain = Aout; Aout = t1;
            float* t2 = Bin; Bin = Bout; Bout = t2;
        }
        float v = (tid == 0) ? 0.f : Bin[tid-1];
        int cand = NT;
        #pragma unroll
        for (int i = 0; i < SC_PER; i++){
            if (t0 + i >= s){
                v = 0.5f*(v + xv[i]);
                vkeep[i] = v;
                if (v >= 1.0f && rv[i] && cand == NT) cand = t0 + i;
            }
        }
        if (tid == 0) smin = NT;
        __syncthreads();
        if (cand < NT) atomicMin(&smin, cand);
        __syncthreads();
        int tmin = smin;
        __syncthreads();
        if (tmin >= NT) break;
        s = tmin + 1;
    }

    int sp[SC_PER]; int cnt_loc = 0;
    #pragma unroll
    for (int i = 0; i < SC_PER; i++){ sp[i] = (vkeep[i] >= 1.0f) ? 1 : 0; cnt_loc += sp[i]; }

    __shared__ int sI[SC_THREADS], sI2[SC_THREADS];
    sI[tid] = cnt_loc;
    __syncthreads();
    int *Iin = sI, *Iout = sI2;
    for (int off = 1; off < SC_THREADS; off <<= 1){
        int vcur = Iin[tid];
        int vpre = (tid >= off) ? Iin[tid-off] : 0;
        Iout[tid] = vcur + vpre;
        __syncthreads();
        int* tt = Iin; Iin = Iout; Iout = tt;
    }
    int c = (tid == 0) ? 0 : Iin[tid-1];

    float wv_[SC_PER]; int id_[SC_PER];
    #pragma unroll
    for (int i = 0; i < SC_PER; i++){
        id_[i] = (c < NK-1) ? c : (NK-1);
        wv_[i] = fmaxf(vkeep[i], 0.f);
        c += sp[i];
    }
    float4* w4 = (float4*)(wout + b*NT + t0);
    w4[0] = make_float4(wv_[0], wv_[1], wv_[2], wv_[3]);
    w4[1] = make_float4(wv_[4], wv_[5], wv_[6], wv_[7]);
    int4* i4 = (int4*)(ids + b*NT + t0);
    i4[0] = make_int4(id_[0], id_[1], id_[2], id_[3]);
    i4[1] = make_int4(id_[4], id_[5], id_[6], id_[7]);
    if (tid == SC_THREADS-1) used[b] = id_[SC_PER-1] + 1;
}

// ---------------------------------------------------------------------------
// K3 phase A: chunked segment pooling (monotone ids, step<=1).
// ---------------------------------------------------------------------------
__global__ __launch_bounds__(128) void k_pool_part(
    const float* __restrict__ h, const float* __restrict__ w,
    const int* __restrict__ ids, float* __restrict__ tok,
    float* __restrict__ pnum, float* __restrict__ pden, int* __restrict__ pid)
{
    const int c   = blockIdx.x;
    const int b   = blockIdx.y;
    const int tid = threadIdx.x;            // 128 = ND
    const int t0  = c * TCH;

    __shared__ int   sid[TCH];
    __shared__ float swt[TCH];
    if (tid < TCH){
        sid[tid] = ids[b*NT + t0 + tid];
        swt[tid] = w  [b*NT + t0 + tid];
    }
    float hbuf[TCH];
    #pragma unroll
    for (int i = 0; i < TCH; i++)
        hbuf[i] = h[((size_t)(b*NT + t0 + i))*ND + tid];
    __syncthreads();

    const int ebase = (b*NCH + c)*2;
    float acc = 0.f, den = 0.f;
    int   cur = sid[0];
    bool  flushed = false;
    #pragma unroll
    for (int i = 0; i < TCH; i++){
        int id = sid[i];
        if (id != cur){
            if (!flushed){
                pnum[(size_t)ebase*ND + tid] = acc;
                if (tid == 0){ pden[ebase] = den; pid[ebase] = cur; }
                flushed = true;
            } else {
                tok[((size_t)(b*NK + cur))*ND + tid] = acc / (den + 1e-8f);
            }
            acc = 0.f; den = 0.f; cur = id;
        }
        acc = fmaf(swt[i], hbuf[i], acc);
        den += swt[i];
    }
    if (!flushed){
        pnum[(size_t)ebase*ND + tid] = acc;
        if (tid == 0){ pden[ebase] = den; pid[ebase] = cur; pid[ebase+1] = -1; }
    } else {
        pnum[((size_t)ebase+1)*ND + tid] = acc;
        if (tid == 0){ pden[ebase+1] = den; pid[ebase+1] = cur; }
    }
}

// ---------------------------------------------------------------------------
// K3 phase B: merge boundary partials in t-order.
// ---------------------------------------------------------------------------
__global__ __launch_bounds__(128) void k_pool_combine(
    const float* __restrict__ pnum, const float* __restrict__ pden,
    const int* __restrict__ pid, float* __restrict__ tok)
{
    const int b   = blockIdx.x;
    const int tid = threadIdx.x;
    int cur = -1; float acc = 0.f, den = 0.f;
    for (int e = 0; e < NCH*2; e++){
        const int gi = b*NCH*2 + e;
        int id = pid[gi];
        if (id < 0) continue;
        float nv = pnum[(size_t)gi*ND + tid];
        float dv = pden[gi];
        if (id == cur){ acc += nv; den += dv; }
        else {
            if (cur >= 0) tok[((size_t)(b*NK + cur))*ND + tid] = acc / (den + 1e-8f);
            cur = id; acc = nv; den = dv;
        }
    }
    if (cur >= 0) tok[((size_t)(b*NK + cur))*ND + tid] = acc / (den + 1e-8f);
}

// ---------------------------------------------------------------------------
// Empty-row constant chain. Stage 1: uvec = gelu(ln1_b @ W1 + b1). 4 blocks,
// deep unroll for load ILP (latency-bound at few-CU occupancy).
// ---------------------------------------------------------------------------
__global__ __launch_bounds__(256) void k_empty_u(
    const float* __restrict__ ln1b, const float* __restrict__ W1,
    const float* __restrict__ b1, float* __restrict__ uvec)
{
    __shared__ float z[ND];
    const int tid = threadIdx.x;
    const int j = blockIdx.x * 256 + tid;
    if (tid < ND) z[tid] = ln1b[tid];
    __syncthreads();
    float a = b1[j];
    #pragma unroll 16
    for (int k = 0; k < ND; k++)
        a = fmaf(z[k], W1[(size_t)k*NH + j], a);
    uvec[j] = gelu_f(a);
}

// Stage 2: grid (12, 4): pvec_part[kq][col] = sum_{k in kq-quarter} u[k]*W2[k][col]
__global__ __launch_bounds__(256) void k_empty_mv(
    const float* __restrict__ uvec, const float* __restrict__ W2,
    float* __restrict__ pvec_part)
{
    __shared__ float su[256];
    __shared__ float part[4][64];
    const int tid = threadIdx.x;
    const int colbase = blockIdx.x * 64;
    const int kq = blockIdx.y;               // 0..3 (256-k quarter)
    const int ksub = tid >> 6;               // 0..3 (64-k slice)
    const int col  = tid & 63;
    su[tid] = uvec[kq*256 + tid];
    __syncthreads();
    float p = 0.f;
    #pragma unroll 8
    for (int k = ksub*64; k < ksub*64 + 64; k++)
        p = fmaf(su[k], W2[(size_t)(kq*256 + k)*NO + colbase + col], p);
    part[ksub][col] = p;
    __syncthreads();
    if (tid < 64)
        pvec_part[kq*NO + colbase + tid] =
            part[0][tid] + part[1][tid] + part[2][tid] + part[3][tid];
}

// Stage 3: cvec = LN2(b2 + sum_q pvec_part[q])   (1 block)
__global__ __launch_bounds__(256) void k_empty_fin(
    const float* __restrict__ pvec_part, const float* __restrict__ b2,
    const float* __restrict__ g2, const float* __restrict__ lb2,
    float* __restrict__ cvec)
{
    __shared__ float red[8];
    const int tid = threadIdx.x;
    float p0 = b2[tid      ], p1 = b2[tid + 256], p2 = b2[tid + 512];
    #pragma unroll
    for (int q = 0; q < 4; q++){
        p0 += pvec_part[q*NO + tid      ];
        p1 += pvec_part[q*NO + tid + 256];
        p2 += pvec_part[q*NO + tid + 512];
    }
    float s = p0+p1+p2, qq = p0*p0 + p1*p1 + p2*p2;
    for (int off = 32; off > 0; off >>= 1){ s += __shfl_xor(s, off); qq += __shfl_xor(qq, off); }
    if ((tid & 63) == 0){ red[tid>>6] = s; red[4 + (tid>>6)] = qq; }
    __syncthreads();
    s  = red[0]+red[1]+red[2]+red[3];
    qq = red[4]+red[5]+red[6]+red[7];
    float m = s * (1.0f/NO);
    float rstd = rsqrtf(qq * (1.0f/NO) - m*m + 1e-5f);
    cvec[tid      ] = (p0 - m)*rstd*g2[tid      ] + lb2[tid      ];
    cvec[tid + 256] = (p1 - m)*rstd*g2[tid + 256] + lb2[tid + 256];
    cvec[tid + 512] = (p2 - m)*rstd*g2[tid + 512] + lb2[tid + 512];
}

// ---------------------------------------------------------------------------
// K4a: fill ALL output rows with the constant row. 1024 blocks x 192 threads;
// each block streams R_FILL=32 contiguous rows (96 KB) -> long-lived blocks,
// deep store pipeline (the old per-4-row copy ran at 900 GB/s, lifetime-bound).
// ---------------------------------------------------------------------------
__global__ __launch_bounds__(192) void k_fill(
    const float* __restrict__ cvec, float* __restrict__ out)
{
    const int tid = threadIdx.x;             // 192 = NO/4
    const size_t r0 = (size_t)blockIdx.x * R_FILL;
    const float4 cv = ((const float4*)cvec)[tid];
    float4* o4 = (float4*)out + r0*(NO/4) + tid;
    #pragma unroll
    for (int r = 0; r < R_FILL; r++)
        o4[(size_t)r*(NO/4)] = cv;
}

// ---------------------------------------------------------------------------
// K4b: full MLP for REAL rows only (k < used[b]); others exit immediately.
// Grid (NK/RKR, NB); break is block-uniform.
// ---------------------------------------------------------------------------
__global__ __launch_bounds__(256) void k_mlp_real(
    const float* __restrict__ tok, const int* __restrict__ used,
    const float* __restrict__ ln1g, const float* __restrict__ ln1b,
    const float* __restrict__ W1, const float* __restrict__ b1,
    const float* __restrict__ W2, const float* __restrict__ b2,
    const float* __restrict__ g2, const float* __restrict__ lb2,
    float* __restrict__ out)
{
    __shared__ float zz[ND];
    __shared__ float su[NH];
    __shared__ float red[8];
    const int tid = threadIdx.x;
    const int b   = blockIdx.y;
    const int k0  = blockIdx.x * RKR;
    const int u   = used[b];
    if (k0 >= u) return;

    for (int kr = 0; kr < RKR; kr++){
        const int k = k0 + kr;
        if (k >= u) break;                   // block-uniform
        float* orow = out + ((size_t)(b*NK + k)) * NO;

        // ---- LN1 over 128 ----
        float tv = 0.f, s = 0.f, qq = 0.f;
        if (tid < ND){
            tv = tok[((size_t)(b*NK + k))*ND + tid];
            s = tv; qq = tv*tv;
        }
        for (int off = 32; off > 0; off >>= 1){ s += __shfl_xor(s, off); qq += __shfl_xor(qq, off); }
        if ((tid & 63) == 0){ red[tid>>6] = s; red[4 + (tid>>6)] = qq; }
        __syncthreads();
        s  = red[0]+red[1]+red[2]+red[3];
        qq = red[4]+red[5]+red[6]+red[7];
        float m = s * (1.0f/ND);
        float rstd = rsqrtf(qq * (1.0f/ND) - m*m + 1e-5f);
        if (tid < ND) zz[tid] = (tv - m)*rstd*ln1g[tid] + ln1b[tid];
        __syncthreads();

        // ---- z @ W1 + b1, gelu -> su[1024] ----
        float4 a = ((const float4*)b1)[tid];
        for (int kk = 0; kk < ND; kk++)
            fma4(a, zz[kk], ((const float4*)W1)[kk*(NH/4) + tid]);
        float4 gg;
        gg.x = gelu_f(a.x); gg.y = gelu_f(a.y); gg.z = gelu_f(a.z); gg.w = gelu_f(a.w);
        ((float4*)su)[tid] = gg;
        __syncthreads();

        // ---- su @ W2 + b2 (768 outs, 3 per thread) ----
        float p0 = b2[tid], p1 = b2[tid+256], p2 = b2[tid+512];
        for (int kk = 0; kk < NH; kk++){
            float uk = su[kk];
            p0 = fmaf(uk, W2[kk*NO + tid      ], p0);
            p1 = fmaf(uk, W2[kk*NO + tid + 256], p1);
            p2 = fmaf(uk, W2[kk*NO + tid + 512], p2);
        }
        // ---- LN2 over 768 ----
        s = p0+p1+p2; qq = p0*p0 + p1*p1 + p2*p2;
        for (int off = 32; off > 0; off >>= 1){ s += __shfl_xor(s, off); qq += __shfl_xor(qq, off); }
        if ((tid & 63) == 0){ red[tid>>6] = s; red[4 + (tid>>6)] = qq; }
        __syncthreads();
        s  = red[0]+red[1]+red[2]+red[3];
        qq = red[4]+red[5]+red[6]+red[7];
        m = s * (1.0f/NO);
        rstd = rsqrtf(qq * (1.0f/NO) - m*m + 1e-5f);
        orow[tid      ] = (p0 - m)*rstd*g2[tid      ] + lb2[tid      ];
        orow[tid + 256] = (p1 - m)*rstd*g2[tid + 256] + lb2[tid + 256];
        orow[tid + 512] = (p2 - m)*rstd*g2[tid + 512] + lb2[tid + 512];
        __syncthreads();   // protect red/zz/su before next row
    }
}

// ---------------------------------------------------------------------------
extern "C" void kernel_launch(void* const* d_in, const int* in_sizes, int n_in,
                              void* d_out, int out_size, void* d_ws, size_t ws_size,
                              hipStream_t stream)
{
    const int*   inp  = (const int*)  d_in[0];
    const float* emb  = (const float*)d_in[1];
    const float* Wc   = (const float*)d_in[2];
    const float* bc   = (const float*)d_in[3];
    const float* lng  = (const float*)d_in[4];
    const float* lnb  = (const float*)d_in[5];
    const float* bndW = (const float*)d_in[6];
    const float* bndB = (const float*)d_in[7];
    const float* rstW = (const float*)d_in[8];
    const float* rstB = (const float*)d_in[9];
    const float* g1   = (const float*)d_in[10];
    const float* b1l  = (const float*)d_in[11];
    const float* W1   = (const float*)d_in[12];
    const float* b1   = (const float*)d_in[13];
    const float* W2   = (const float*)d_in[14];
    const float* b2   = (const float*)d_in[15];
    const float* g2   = (const float*)d_in[16];
    const float* lb2  = (const float*)d_in[17];

    char* ws = (char*)d_ws;
    // ws layout (all offsets 256B-aligned); total = 34,614,528 bytes
    float* h    = (float*)(ws + 0);          // NR*ND*4   = 16,777,216
    float* xq   = (float*)(ws + 16777216);   // NR*4      =    131,072
    int*   rm   = (int*)  (ws + 16908288);   // NR*4
    float* wv   = (float*)(ws + 17039360);   // NR*4
    int*   ids  = (int*)  (ws + 17170432);   // NR*4
    int*   usd  = (int*)  (ws + 17301504);   // NB*4 (padded to 256)
    float* cvec = (float*)(ws + 17301760);   // NO*4 = 3072
    float* tok  = (float*)(ws + 17304832);   // NB*NK*ND*4 = 16,777,216
    float* pnum = (float*)(ws + 34082048);   // NB*NCH*2*ND*4 = 524,288
    float* pden = (float*)(ws + 34606336);   // NB*NCH*2*4 = 4,096
    int*   pid  = (int*)  (ws + 34610432);   // NB*NCH*2*4 = 4,096
    // uvec/pvec_part reuse xq's region (xq dead after k_scan; chain runs later)
    float* uvec = (float*)(ws + 16777216);       // NH*4 = 4,096
    float* pvpt = (float*)(ws + 16777216+4096);  // 4*NO*4 = 12,288

    float* out = (float*)d_out;

    k_embed_ctx<<<dim3(NR / K1_ROWS), dim3(256), 0, stream>>>(
        inp, emb, Wc, bc, lng, lnb, bndW, bndB, rstW, rstB, h, xq, rm);
    k_scan<<<dim3(NB), dim3(SC_THREADS), 0, stream>>>(xq, rm, wv, ids, usd);
    k_pool_part<<<dim3(NCH, NB), dim3(128), 0, stream>>>(
        h, wv, ids, tok, pnum, pden, pid);
    k_pool_combine<<<dim3(NB), dim3(128), 0, stream>>>(pnum, pden, pid, tok);
    k_empty_u<<<dim3(NH/256), dim3(256), 0, stream>>>(b1l, W1, b1, uvec);
    k_empty_mv<<<dim3(NO/64, 4), dim3(256), 0, stream>>>(uvec, W2, pvpt);
    k_empty_fin<<<dim3(1), dim3(256), 0, stream>>>(pvpt, b2, g2, lb2, cvec);
    k_fill<<<dim3(NR / R_FILL), dim3(192), 0, stream>>>(cvec, out);
    k_mlp_real<<<dim3(NK / RKR, NB), dim3(256), 0, stream>>>(
        tok, usd, g1, b1l, W1, b1, W2, b2, g2, lb2, out);
}

// Round 11
// 238.464 us; speedup vs baseline: 1.4670x; 1.4670x over previous
//
#include <hip/hip_runtime.h>
#include <hip/hip_bf16.h>
#include <math.h>

// Problem dims (fixed by the reference)
#define NB 16
#define NT 2048
#define NR (NB*NT)     // 32768 rows
#define ND 128
#define NH 1024
#define NO 768
#define NK NT          // segment capacity K = T
#define K1_ROWS 32
#define NCH 32         // k_pool chunks per batch
#define TCH (NT/NCH)   // 64 t-steps per pool chunk
#define SC_THREADS 256
#define SC_PER (NT/SC_THREADS)   // 8
#define R_FILL 32      // rows per fill block
#define RKR 16         // candidate rows per tail block
#define RM1PB 16       // tier-1 real rows per batch
#define RMAX1 (NB*RM1PB)  // 256
#define KCH 16         // k-chunks (64 k each) for W2 matvec split

__device__ __forceinline__ float gelu_f(float x){
    // exact gelu: x * 0.5 * (1 + erf(x/sqrt(2)))
    return 0.5f * x * (1.0f + erff(x * 0.70710678118654752440f));
}
__device__ __forceinline__ void fma4(float4& a, float s, float4 w){
    a.x = fmaf(s, w.x, a.x);
    a.y = fmaf(s, w.y, a.y);
    a.z = fmaf(s, w.z, a.z);
    a.w = fmaf(s, w.w, a.w);
}

// ---------------------------------------------------------------------------
// K1: embedding gather + (row @ ctx_W + b) + LayerNorm + GELU + bnd/rst dots
// ---------------------------------------------------------------------------
__global__ __launch_bounds__(256) void k_embed_ctx(
    const int* __restrict__ inp, const float* __restrict__ emb,
    const float* __restrict__ Wc, const float* __restrict__ bc,
    const float* __restrict__ lng, const float* __restrict__ lnb,
    const float* __restrict__ bndW, const float* __restrict__ bndB,
    const float* __restrict__ rstW, const float* __restrict__ rstB,
    float* __restrict__ hout, float* __restrict__ xseq, int* __restrict__ rmask)
{
    __shared__ float sE[K1_ROWS][ND];   // 16 KB
    const int tid = threadIdx.x;
    const int r0 = blockIdx.x * K1_ROWS;

    #pragma unroll
    for (int q = 0; q < 4; q++){
        int fidx = tid + 256*q;
        int row  = fidx >> 5;
        int c4   = fidx & 31;
        int tokv = inp[r0 + row];
        float4 ev = make_float4(0.f, 0.f, 0.f, 0.f);
        if (tokv != 0) ev = ((const float4*)emb)[tokv*(ND/4) + c4];
        ((float4*)(&sE[row][0]))[c4] = ev;
    }
    __syncthreads();

    const int bun  = tid >> 5;
    const int lane = tid & 31;
    const int jo   = lane * 4;
    const int rbse = bun * 4;

    float4 acc0 = make_float4(0,0,0,0);
    float4 acc1 = acc0, acc2 = acc0, acc3 = acc0;

    for (int k0 = 0; k0 < ND; k0 += 4){
        float4 e0 = *(const float4*)&sE[rbse+0][k0];
        float4 e1 = *(const float4*)&sE[rbse+1][k0];
        float4 e2 = *(const float4*)&sE[rbse+2][k0];
        float4 e3 = *(const float4*)&sE[rbse+3][k0];
        float4 w0 = *(const float4*)&Wc[(k0+0)*ND + jo];
        float4 w1 = *(const float4*)&Wc[(k0+1)*ND + jo];
        float4 w2 = *(const float4*)&Wc[(k0+2)*ND + jo];
        float4 w3 = *(const float4*)&Wc[(k0+3)*ND + jo];
        fma4(acc0, e0.x, w0); fma4(acc0, e0.y, w1); fma4(acc0, e0.z, w2); fma4(acc0, e0.w, w3);
        fma4(acc1, e1.x, w0); fma4(acc1, e1.y, w1); fma4(acc1, e1.z, w2); fma4(acc1, e1.w, w3);
        fma4(acc2, e2.x, w0); fma4(acc2, e2.y, w1); fma4(acc2, e2.z, w2); fma4(acc2, e2.w, w3);
        fma4(acc3, e3.x, w0); fma4(acc3, e3.y, w1); fma4(acc3, e3.z, w2); fma4(acc3, e3.w, w3);
    }

    const float4 cb  = ((const float4*)bc)[lane];
    const float4 gv  = ((const float4*)lng)[lane];
    const float4 bv  = ((const float4*)lnb)[lane];
    const float4 bwv = ((const float4*)bndW)[lane];
    const float4 rwv = ((const float4*)rstW)[lane];
    const float bb0 = bndB[0], rr0 = rstB[0];

    #define K1_EPI(ACC, RR) do { \
        float4 a = ACC; \
        a.x += cb.x; a.y += cb.y; a.z += cb.z; a.w += cb.w; \
        float s_ = a.x + a.y + a.z + a.w; \
        float q_ = a.x*a.x + a.y*a.y + a.z*a.z + a.w*a.w; \
        for (int off = 16; off > 0; off >>= 1){ s_ += __shfl_xor(s_, off, 32); q_ += __shfl_xor(q_, off, 32); } \
        float m_ = s_ * (1.0f/ND); \
        float rstd_ = rsqrtf(q_ * (1.0f/ND) - m_*m_ + 1e-5f); \
        float4 hh; \
        hh.x = gelu_f((a.x - m_)*rstd_*gv.x + bv.x); \
        hh.y = gelu_f((a.y - m_)*rstd_*gv.y + bv.y); \
        hh.z = gelu_f((a.z - m_)*rstd_*gv.z + bv.z); \
        hh.w = gelu_f((a.w - m_)*rstd_*gv.w + bv.w); \
        *(float4*)&hout[(size_t)(r0 + rbse + RR)*ND + jo] = hh; \
        float pb = hh.x*bwv.x + hh.y*bwv.y + hh.z*bwv.z + hh.w*bwv.w; \
        float pr = hh.x*rwv.x + hh.y*rwv.y + hh.z*rwv.z + hh.w*rwv.w; \
        for (int off = 16; off > 0; off >>= 1){ pb += __shfl_xor(pb, off, 32); pr += __shfl_xor(pr, off, 32); } \
        if (lane == 0){ \
            int rg = r0 + rbse + RR; \
            xseq[rg]  = tanhf(pb + bb0); \
            rmask[rg] = (pr + rr0) > 0.f ? 1 : 0; \
        } \
    } while(0)

    K1_EPI(acc0, 0); K1_EPI(acc1, 1); K1_EPI(acc2, 2); K1_EPI(acc3, 3);
    #undef K1_EPI
}

// ---------------------------------------------------------------------------
// K2: parallel speculative LIF scan (affine charge; speculate-and-restart on
// conditional reset; converges in 1 pass when no (spike && reset)).
// ---------------------------------------------------------------------------
__global__ __launch_bounds__(SC_THREADS) void k_scan(
    const float* __restrict__ x, const int* __restrict__ rm,
    float* __restrict__ wout, int* __restrict__ ids, int* __restrict__ used)
{
    const int b   = blockIdx.x;
    const int tid = threadIdx.x;
    const int t0  = tid * SC_PER;

    float xv[SC_PER];
    int   rv[SC_PER];
    {
        const float4* xb4 = (const float4*)(x + b*NT + t0);
        float4 xa = xb4[0], xb = xb4[1];
        xv[0]=xa.x; xv[1]=xa.y; xv[2]=xa.z; xv[3]=xa.w;
        xv[4]=xb.x; xv[5]=xb.y; xv[6]=xb.z; xv[7]=xb.w;
        const int4* rb4 = (const int4*)(rm + b*NT + t0);
        int4 r0_ = rb4[0], r1_ = rb4[1];
        rv[0]=r0_.x; rv[1]=r0_.y; rv[2]=r0_.z; rv[3]=r0_.w;
        rv[4]=r1_.x; rv[5]=r1_.y; rv[6]=r1_.z; rv[7]=r1_.w;
    }

    __shared__ float sA[SC_THREADS], sB[SC_THREADS];
    __shared__ float sA2[SC_THREADS], sB2[SC_THREADS];
    __shared__ int   smin;

    float vkeep[SC_PER];
    #pragma unroll
    for (int i = 0; i < SC_PER; i++) vkeep[i] = 0.f;

    int s = 0;
    while (true){
        float aL = 1.f, bL = 0.f;
        #pragma unroll
        for (int i = 0; i < SC_PER; i++){
            if (t0 + i >= s){
                aL *= 0.5f;
                bL = 0.5f*(bL + xv[i]);
            }
        }
        sA[tid] = aL; sB[tid] = bL;
        __syncthreads();
        float *Ain = sA, *Bin = sB, *Aout = sA2, *Bout = sB2;
        for (int off = 1; off < SC_THREADS; off <<= 1){
            float a_cur = Ain[tid], b_cur = Bin[tid];
            float a_pre = 1.f, b_pre = 0.f;
            if (tid >= off){ a_pre = Ain[tid-off]; b_pre = Bin[tid-off]; }
            Aout[tid] = a_pre * a_cur;
            Bout[tid] = fmaf(a_cur, b_pre, b_cur);
            __syncthreads();
            float* t1 = Ain; Ain = Aout; Aout = t1;
            float* t2 = Bin; Bin = Bout; Bout = t2;
        }
        float v = (tid == 0) ? 0.f : Bin[tid-1];
        int cand = NT;
        #pragma unroll
        for (int i = 0; i < SC_PER; i++){
            if (t0 + i >= s){
                v = 0.5f*(v + xv[i]);
                vkeep[i] = v;
                if (v >= 1.0f && rv[i] && cand == NT) cand = t0 + i;
            }
        }
        if (tid == 0) smin = NT;
        __syncthreads();
        if (cand < NT) atomicMin(&smin, cand);
        __syncthreads();
        int tmin = smin;
        __syncthreads();
        if (tmin >= NT) break;
        s = tmin + 1;
    }

    int sp[SC_PER]; int cnt_loc = 0;
    #pragma unroll
    for (int i = 0; i < SC_PER; i++){ sp[i] = (vkeep[i] >= 1.0f) ? 1 : 0; cnt_loc += sp[i]; }

    __shared__ int sI[SC_THREADS], sI2[SC_THREADS];
    sI[tid] = cnt_loc;
    __syncthreads();
    int *Iin = sI, *Iout = sI2;
    for (int off = 1; off < SC_THREADS; off <<= 1){
        int vcur = Iin[tid];
        int vpre = (tid >= off) ? Iin[tid-off] : 0;
        Iout[tid] = vcur + vpre;
        __syncthreads();
        int* tt = Iin; Iin = Iout; Iout = tt;
    }
    int c = (tid == 0) ? 0 : Iin[tid-1];

    float wv_[SC_PER]; int id_[SC_PER];
    #pragma unroll
    for (int i = 0; i < SC_PER; i++){
        id_[i] = (c < NK-1) ? c : (NK-1);
        wv_[i] = fmaxf(vkeep[i], 0.f);
        c += sp[i];
    }
    float4* w4 = (float4*)(wout + b*NT + t0);
    w4[0] = make_float4(wv_[0], wv_[1], wv_[2], wv_[3]);
    w4[1] = make_float4(wv_[4], wv_[5], wv_[6], wv_[7]);
    int4* i4 = (int4*)(ids + b*NT + t0);
    i4[0] = make_int4(id_[0], id_[1], id_[2], id_[3]);
    i4[1] = make_int4(id_[4], id_[5], id_[6], id_[7]);
    if (tid == SC_THREADS-1) used[b] = id_[SC_PER-1] + 1;
}

// ---------------------------------------------------------------------------
// K3 phase A: chunked segment pooling (monotone ids, step<=1).
// ---------------------------------------------------------------------------
__global__ __launch_bounds__(128) void k_pool_part(
    const float* __restrict__ h, const float* __restrict__ w,
    const int* __restrict__ ids, float* __restrict__ tok,
    float* __restrict__ pnum, float* __restrict__ pden, int* __restrict__ pid)
{
    const int c   = blockIdx.x;
    const int b   = blockIdx.y;
    const int tid = threadIdx.x;            // 128 = ND
    const int t0  = c * TCH;

    __shared__ int   sid[TCH];
    __shared__ float swt[TCH];
    if (tid < TCH){
        sid[tid] = ids[b*NT + t0 + tid];
        swt[tid] = w  [b*NT + t0 + tid];
    }
    float hbuf[TCH];
    #pragma unroll
    for (int i = 0; i < TCH; i++)
        hbuf[i] = h[((size_t)(b*NT + t0 + i))*ND + tid];
    __syncthreads();

    const int ebase = (b*NCH + c)*2;
    float acc = 0.f, den = 0.f;
    int   cur = sid[0];
    bool  flushed = false;
    #pragma unroll
    for (int i = 0; i < TCH; i++){
        int id = sid[i];
        if (id != cur){
            if (!flushed){
                pnum[(size_t)ebase*ND + tid] = acc;
                if (tid == 0){ pden[ebase] = den; pid[ebase] = cur; }
                flushed = true;
            } else {
                tok[((size_t)(b*NK + cur))*ND + tid] = acc / (den + 1e-8f);
            }
            acc = 0.f; den = 0.f; cur = id;
        }
        acc = fmaf(swt[i], hbuf[i], acc);
        den += swt[i];
    }
    if (!flushed){
        pnum[(size_t)ebase*ND + tid] = acc;
        if (tid == 0){ pden[ebase] = den; pid[ebase] = cur; pid[ebase+1] = -1; }
    } else {
        pnum[((size_t)ebase+1)*ND + tid] = acc;
        if (tid == 0){ pden[ebase+1] = den; pid[ebase+1] = cur; }
    }
}

// ---------------------------------------------------------------------------
// K3 phase B: merge boundary partials in t-order.
// ---------------------------------------------------------------------------
__global__ __launch_bounds__(128) void k_pool_combine(
    const float* __restrict__ pnum, const float* __restrict__ pden,
    const int* __restrict__ pid, float* __restrict__ tok)
{
    const int b   = blockIdx.x;
    const int tid = threadIdx.x;
    int cur = -1; float acc = 0.f, den = 0.f;
    for (int e = 0; e < NCH*2; e++){
        const int gi = b*NCH*2 + e;
        int id = pid[gi];
        if (id < 0) continue;
        float nv = pnum[(size_t)gi*ND + tid];
        float dv = pden[gi];
        if (id == cur){ acc += nv; den += dv; }
        else {
            if (cur >= 0) tok[((size_t)(b*NK + cur))*ND + tid] = acc / (den + 1e-8f);
            cur = id; acc = nv; den = dv;
        }
    }
    if (cur >= 0) tok[((size_t)(b*NK + cur))*ND + tid] = acc / (den + 1e-8f);
}

// ---------------------------------------------------------------------------
// Empty-row constant chain (cvec for all-zero segments).
// ---------------------------------------------------------------------------
__global__ __launch_bounds__(256) void k_empty_u(
    const float* __restrict__ ln1b, const float* __restrict__ W1,
    const float* __restrict__ b1, float* __restrict__ uvec)
{
    __shared__ float z[ND];
    const int tid = threadIdx.x;
    const int j = blockIdx.x * 256 + tid;
    if (tid < ND) z[tid] = ln1b[tid];
    __syncthreads();
    float a = b1[j];
    #pragma unroll 16
    for (int k = 0; k < ND; k++)
        a = fmaf(z[k], W1[(size_t)k*NH + j], a);
    uvec[j] = gelu_f(a);
}

__global__ __launch_bounds__(256) void k_empty_mv(
    const float* __restrict__ uvec, const float* __restrict__ W2,
    float* __restrict__ pvec_part)
{
    __shared__ float su[256];
    __shared__ float part[4][64];
    const int tid = threadIdx.x;
    const int colbase = blockIdx.x * 64;
    const int kq = blockIdx.y;               // 0..3 (256-k quarter)
    const int ksub = tid >> 6;               // 0..3 (64-k slice)
    const int col  = tid & 63;
    su[tid] = uvec[kq*256 + tid];
    __syncthreads();
    float p = 0.f;
    #pragma unroll 8
    for (int k = ksub*64; k < ksub*64 + 64; k++)
        p = fmaf(su[k], W2[(size_t)(kq*256 + k)*NO + colbase + col], p);
    part[ksub][col] = p;
    __syncthreads();
    if (tid < 64)
        pvec_part[kq*NO + colbase + tid] =
            part[0][tid] + part[1][tid] + part[2][tid] + part[3][tid];
}

__global__ __launch_bounds__(256) void k_empty_fin(
    const float* __restrict__ pvec_part, const float* __restrict__ b2,
    const float* __restrict__ g2, const float* __restrict__ lb2,
    float* __restrict__ cvec)
{
    __shared__ float red[8];
    const int tid = threadIdx.x;
    float p0 = b2[tid      ], p1 = b2[tid + 256], p2 = b2[tid + 512];
    #pragma unroll
    for (int q = 0; q < 4; q++){
        p0 += pvec_part[q*NO + tid      ];
        p1 += pvec_part[q*NO + tid + 256];
        p2 += pvec_part[q*NO + tid + 512];
    }
    float s = p0+p1+p2, qq = p0*p0 + p1*p1 + p2*p2;
    for (int off = 32; off > 0; off >>= 1){ s += __shfl_xor(s, off); qq += __shfl_xor(qq, off); }
    if ((tid & 63) == 0){ red[tid>>6] = s; red[4 + (tid>>6)] = qq; }
    __syncthreads();
    s  = red[0]+red[1]+red[2]+red[3];
    qq = red[4]+red[5]+red[6]+red[7];
    float m = s * (1.0f/NO);
    float rstd = rsqrtf(qq * (1.0f/NO) - m*m + 1e-5f);
    cvec[tid      ] = (p0 - m)*rstd*g2[tid      ] + lb2[tid      ];
    cvec[tid + 256] = (p1 - m)*rstd*g2[tid + 256] + lb2[tid + 256];
    cvec[tid + 512] = (p2 - m)*rstd*g2[tid + 512] + lb2[tid + 512];
}

// ---------------------------------------------------------------------------
// Real-row chain. k_rows: compact (b,k) list of tier-1 rows (k < min(u,16)).
// ---------------------------------------------------------------------------
__global__ void k_rows(const int* __restrict__ used, int* __restrict__ rmeta,
                       int* __restrict__ rlist)
{
    if (threadIdx.x == 0){
        int n = 0;
        for (int b = 0; b < NB; b++){
            int u = used[b]; int m = u < RM1PB ? u : RM1PB;
            for (int k = 0; k < m; k++) rlist[n++] = (b<<16) | k;
        }
        rmeta[0] = n;
    }
}

// k_ureal: per real row, 4 blocks compute u = gelu(LN1(tok)@W1+b1), 256 j each.
__global__ __launch_bounds__(256) void k_ureal(
    const int* __restrict__ rmeta, const int* __restrict__ rlist,
    const float* __restrict__ tok,
    const float* __restrict__ ln1g, const float* __restrict__ ln1b,
    const float* __restrict__ W1, const float* __restrict__ b1,
    float* __restrict__ ubuf)
{
    const int i = blockIdx.x;
    if (i >= rmeta[0]) return;
    const int q   = blockIdx.y;
    const int tid = threadIdx.x;
    const int bk  = rlist[i];
    const int b = bk >> 16, k = bk & 0xffff;

    __shared__ float zz[ND];
    __shared__ float red[8];
    float tv = 0.f, s = 0.f, qq = 0.f;
    if (tid < ND){
        tv = tok[((size_t)(b*NK + k))*ND + tid];
        s = tv; qq = tv*tv;
    }
    for (int off = 32; off > 0; off >>= 1){ s += __shfl_xor(s, off); qq += __shfl_xor(qq, off); }
    if ((tid & 63) == 0){ red[tid>>6] = s; red[4 + (tid>>6)] = qq; }
    __syncthreads();
    s  = red[0]+red[1]+red[2]+red[3];
    qq = red[4]+red[5]+red[6]+red[7];
    float m = s * (1.0f/ND);
    float rstd = rsqrtf(qq * (1.0f/ND) - m*m + 1e-5f);
    if (tid < ND) zz[tid] = (tv - m)*rstd*ln1g[tid] + ln1b[tid];
    __syncthreads();

    const int j = q*256 + tid;
    float a = b1[j];
    #pragma unroll 8
    for (int kk = 0; kk < ND; kk++)
        a = fmaf(zz[kk], W1[(size_t)kk*NH + j], a);
    ubuf[(size_t)i*NH + j] = gelu_f(a);
}

// k_preal: W2 matvec for all tier-1 rows, split (12 colblk x 16 kchunk).
__global__ __launch_bounds__(256) void k_preal(
    const int* __restrict__ rmeta, const float* __restrict__ ubuf,
    const float* __restrict__ W2, float* __restrict__ pbuf)
{
    const int cb  = blockIdx.x;              // 0..11
    const int kc  = blockIdx.y;              // 0..15
    const int tid = threadIdx.x;
    const int ksub = tid >> 6;               // 0..3
    const int col  = tid & 63;
    const int R1 = rmeta[0];
    const int colg  = cb*64 + col;
    const int kbase = kc*64 + ksub*16;

    float w2v[16];
    #pragma unroll
    for (int t = 0; t < 16; t++)
        w2v[t] = W2[(size_t)(kbase + t)*NO + colg];

    __shared__ float part[4][64];
    for (int i = 0; i < R1; i++){
        const float* ui = ubuf + (size_t)i*NH + kbase;
        float p = 0.f;
        #pragma unroll
        for (int t = 0; t < 16; t++) p = fmaf(ui[t], w2v[t], p);
        part[ksub][col] = p;
        __syncthreads();
        if (ksub == 0)
            pbuf[((size_t)kc*RMAX1 + i)*NO + colg] =
                part[0][col] + part[1][col] + part[2][col] + part[3][col];
        __syncthreads();
    }
}

// k_finreal: sum 16 partials + b2, LN2, write the real row (after k_fill).
__global__ __launch_bounds__(256) void k_finreal(
    const int* __restrict__ rmeta, const int* __restrict__ rlist,
    const float* __restrict__ pbuf, const float* __restrict__ b2,
    const float* __restrict__ g2, const float* __restrict__ lb2,
    float* __restrict__ out)
{
    const int i = blockIdx.x;
    if (i >= rmeta[0]) return;
    const int tid = threadIdx.x;
    const int bk  = rlist[i];
    const int b = bk >> 16, k = bk & 0xffff;

    __shared__ float red[8];
    float p0 = b2[tid], p1 = b2[tid+256], p2 = b2[tid+512];
    #pragma unroll
    for (int kc = 0; kc < KCH; kc++){
        const float* pp = pbuf + ((size_t)kc*RMAX1 + i)*NO;
        p0 += pp[tid]; p1 += pp[tid+256]; p2 += pp[tid+512];
    }
    float s = p0+p1+p2, qq = p0*p0 + p1*p1 + p2*p2;
    for (int off = 32; off > 0; off >>= 1){ s += __shfl_xor(s, off); qq += __shfl_xor(qq, off); }
    if ((tid & 63) == 0){ red[tid>>6] = s; red[4 + (tid>>6)] = qq; }
    __syncthreads();
    s  = red[0]+red[1]+red[2]+red[3];
    qq = red[4]+red[5]+red[6]+red[7];
    float m = s * (1.0f/NO);
    float rstd = rsqrtf(qq * (1.0f/NO) - m*m + 1e-5f);
    float* orow = out + ((size_t)(b*NK + k))*NO;
    orow[tid      ] = (p0 - m)*rstd*g2[tid      ] + lb2[tid      ];
    orow[tid + 256] = (p1 - m)*rstd*g2[tid + 256] + lb2[tid + 256];
    orow[tid + 512] = (p2 - m)*rstd*g2[tid + 512] + lb2[tid + 512];
}

// ---------------------------------------------------------------------------
// K4a: fill ALL output rows with the constant row (deep store pipeline).
// ---------------------------------------------------------------------------
__global__ __launch_bounds__(192) void k_fill(
    const float* __restrict__ cvec, float* __restrict__ out)
{
    const int tid = threadIdx.x;             // 192 = NO/4
    const size_t r0 = (size_t)blockIdx.x * R_FILL;
    const float4 cv = ((const float4*)cvec)[tid];
    float4* o4 = (float4*)out + r0*(NO/4) + tid;
    #pragma unroll
    for (int r = 0; r < R_FILL; r++)
        o4[(size_t)r*(NO/4)] = cv;
}

// ---------------------------------------------------------------------------
// Tier-2 tail: rows k in [RM1PB, used[b]) — never runs in practice (v<1 =>
// used==1), kept for worst-case correctness. Old serial per-row MLP.
// ---------------------------------------------------------------------------
__global__ __launch_bounds__(256) void k_mlp_tail(
    const float* __restrict__ tok, const int* __restrict__ used,
    const float* __restrict__ ln1g, const float* __restrict__ ln1b,
    const float* __restrict__ W1, const float* __restrict__ b1,
    const float* __restrict__ W2, const float* __restrict__ b2,
    const float* __restrict__ g2, const float* __restrict__ lb2,
    float* __restrict__ out)
{
    __shared__ float zz[ND];
    __shared__ float su[NH];
    __shared__ float red[8];
    const int tid = threadIdx.x;
    const int b   = blockIdx.y;
    const int k0  = RM1PB + blockIdx.x * RKR;
    const int u   = used[b];
    if (k0 >= u) return;

    for (int kr = 0; kr < RKR; kr++){
        const int k = k0 + kr;
        if (k >= u) break;                   // block-uniform
        float* orow = out + ((size_t)(b*NK + k)) * NO;

        float tv = 0.f, s = 0.f, qq = 0.f;
        if (tid < ND){
            tv = tok[((size_t)(b*NK + k))*ND + tid];
            s = tv; qq = tv*tv;
        }
        for (int off = 32; off > 0; off >>= 1){ s += __shfl_xor(s, off); qq += __shfl_xor(qq, off); }
        if ((tid & 63) == 0){ red[tid>>6] = s; red[4 + (tid>>6)] = qq; }
        __syncthreads();
        s  = red[0]+red[1]+red[2]+red[3];
        qq = red[4]+red[5]+red[6]+red[7];
        float m = s * (1.0f/ND);
        float rstd = rsqrtf(qq * (1.0f/ND) - m*m + 1e-5f);
        if (tid < ND) zz[tid] = (tv - m)*rstd*ln1g[tid] + ln1b[tid];
        __syncthreads();

        float4 a = ((const float4*)b1)[tid];
        for (int kk = 0; kk < ND; kk++)
            fma4(a, zz[kk], ((const float4*)W1)[kk*(NH/4) + tid]);
        float4 gg;
        gg.x = gelu_f(a.x); gg.y = gelu_f(a.y); gg.z = gelu_f(a.z); gg.w = gelu_f(a.w);
        ((float4*)su)[tid] = gg;
        __syncthreads();

        float p0 = b2[tid], p1 = b2[tid+256], p2 = b2[tid+512];
        for (int kk = 0; kk < NH; kk++){
            float uk = su[kk];
            p0 = fmaf(uk, W2[kk*NO + tid      ], p0);
            p1 = fmaf(uk, W2[kk*NO + tid + 256], p1);
            p2 = fmaf(uk, W2[kk*NO + tid + 512], p2);
        }
        s = p0+p1+p2; qq = p0*p0 + p1*p1 + p2*p2;
        for (int off = 32; off > 0; off >>= 1){ s += __shfl_xor(s, off); qq += __shfl_xor(qq, off); }
        if ((tid & 63) == 0){ red[tid>>6] = s; red[4 + (tid>>6)] = qq; }
        __syncthreads();
        s  = red[0]+red[1]+red[2]+red[3];
        qq = red[4]+red[5]+red[6]+red[7];
        m = s * (1.0f/NO);
        rstd = rsqrtf(qq * (1.0f/NO) - m*m + 1e-5f);
        orow[tid      ] = (p0 - m)*rstd*g2[tid      ] + lb2[tid      ];
        orow[tid + 256] = (p1 - m)*rstd*g2[tid + 256] + lb2[tid + 256];
        orow[tid + 512] = (p2 - m)*rstd*g2[tid + 512] + lb2[tid + 512];
        __syncthreads();
    }
}

// ---------------------------------------------------------------------------
extern "C" void kernel_launch(void* const* d_in, const int* in_sizes, int n_in,
                              void* d_out, int out_size, void* d_ws, size_t ws_size,
                              hipStream_t stream)
{
    const int*   inp  = (const int*)  d_in[0];
    const float* emb  = (const float*)d_in[1];
    const float* Wc   = (const float*)d_in[2];
    const float* bc   = (const float*)d_in[3];
    const float* lng  = (const float*)d_in[4];
    const float* lnb  = (const float*)d_in[5];
    const float* bndW = (const float*)d_in[6];
    const float* bndB = (const float*)d_in[7];
    const float* rstW = (const float*)d_in[8];
    const float* rstB = (const float*)d_in[9];
    const float* g1   = (const float*)d_in[10];
    const float* b1l  = (const float*)d_in[11];
    const float* W1   = (const float*)d_in[12];
    const float* b1   = (const float*)d_in[13];
    const float* W2   = (const float*)d_in[14];
    const float* b2   = (const float*)d_in[15];
    const float* g2   = (const float*)d_in[16];
    const float* lb2  = (const float*)d_in[17];

    char* ws = (char*)d_ws;
    // ws layout (all offsets 256B-aligned); total = 34,614,528 bytes
    float* h    = (float*)(ws + 0);          // NR*ND*4   = 16,777,216
    float* xq   = (float*)(ws + 16777216);   // NR*4      =    131,072
    int*   rm   = (int*)  (ws + 16908288);   // NR*4
    float* wv   = (float*)(ws + 17039360);   // NR*4
    int*   ids  = (int*)  (ws + 17170432);   // NR*4
    int*   usd  = (int*)  (ws + 17301504);   // NB*4 (padded to 256)
    float* cvec = (float*)(ws + 17301760);   // NO*4 = 3072
    float* tok  = (float*)(ws + 17304832);   // NB*NK*ND*4 = 16,777,216
    float* pnum = (float*)(ws + 34082048);   // NB*NCH*2*ND*4 = 524,288
    float* pden = (float*)(ws + 34606336);   // NB*NCH*2*4 = 4,096
    int*   pid  = (int*)  (ws + 34610432);   // NB*NCH*2*4 = 4,096
    // reuse xq region (dead after k_scan): empty-chain + row list
    float* uvec  = (float*)(ws + 16777216);          // NH*4 = 4,096
    float* pvpt  = (float*)(ws + 16777216 + 4096);   // 4*NO*4 = 12,288
    int*   rmeta = (int*)  (ws + 16777216 + 16384);  // 4 B (pad 256)
    int*   rlist = (int*)  (ws + 16777216 + 16640);  // RMAX1*4 = 1,024
    // reuse h region (dead after k_pool_part): real-row MLP buffers
    float* ubuf = (float*)(ws + 0);                  // RMAX1*NH*4 = 1,048,576
    float* pbuf = (float*)(ws + 1048576);            // KCH*RMAX1*NO*4 = 12,582,912

    float* out = (float*)d_out;

    k_embed_ctx<<<dim3(NR / K1_ROWS), dim3(256), 0, stream>>>(
        inp, emb, Wc, bc, lng, lnb, bndW, bndB, rstW, rstB, h, xq, rm);
    k_scan<<<dim3(NB), dim3(SC_THREADS), 0, stream>>>(xq, rm, wv, ids, usd);
    k_pool_part<<<dim3(NCH, NB), dim3(128), 0, stream>>>(
        h, wv, ids, tok, pnum, pden, pid);
    k_pool_combine<<<dim3(NB), dim3(128), 0, stream>>>(pnum, pden, pid, tok);
    k_rows<<<dim3(1), dim3(64), 0, stream>>>(usd, rmeta, rlist);
    k_empty_u<<<dim3(NH/256), dim3(256), 0, stream>>>(b1l, W1, b1, uvec);
    k_empty_mv<<<dim3(NO/64, 4), dim3(256), 0, stream>>>(uvec, W2, pvpt);
    k_empty_fin<<<dim3(1), dim3(256), 0, stream>>>(pvpt, b2, g2, lb2, cvec);
    k_ureal<<<dim3(RMAX1, 4), dim3(256), 0, stream>>>(
        rmeta, rlist, tok, g1, b1l, W1, b1, ubuf);
    k_preal<<<dim3(NO/64, KCH), dim3(256), 0, stream>>>(rmeta, ubuf, W2, pbuf);
    k_fill<<<dim3(NR / R_FILL), dim3(192), 0, stream>>>(cvec, out);
    k_finreal<<<dim3(RMAX1), dim3(256), 0, stream>>>(
        rmeta, rlist, pbuf, b2, g2, lb2, out);
    k_mlp_tail<<<dim3((NK - RM1PB) / RKR, NB), dim3(256), 0, stream>>>(
        tok, usd, g1, b1l, W1, b1, W2, b2, g2, lb2, out);
}